// Round 9
// baseline (268.252 us; speedup 1.0000x reference)
//
#include <hip/hip_runtime.h>
#include <hip/hip_bf16.h>

// ============ DIAGNOSTIC ROUND: REP=4 idempotent amplification ============
// agg, gru, and K1's hA branch repeat their body 4x (same outputs) so their
// true durations appear in the top-5 rocprof table. Strip REP next round.
#define REP 4

#define D 256
#define CAP 64          // per-atom bucket capacity; P(degree>64)<1e-15 for E=160K,N=10K

typedef __attribute__((ext_vector_type(8))) short bf16x8;
typedef __attribute__((ext_vector_type(4))) short s16x4;
typedef __attribute__((ext_vector_type(4))) float f32x4;

#define MFMA __builtin_amdgcn_mfma_f32_16x16x32_bf16

__device__ __forceinline__ float s2f(short u) {
    union { unsigned int i; float f; } c;
    c.i = ((unsigned int)(unsigned short)u) << 16;
    return c.f;
}
__device__ __forceinline__ short f2s(float f) {
    union { float f; unsigned int u; } c; c.f = f;
    unsigned int u = c.u;
    u += 0x7fffu + ((u >> 16) & 1u);
    return (short)(u >> 16);
}
// convert 8 contiguous f32 -> bf16x8
__device__ __forceinline__ bf16x8 cvt8(const float* p) {
    float4 f0 = *(const float4*)p;
    float4 f1 = *(const float4*)(p + 4);
    bf16x8 r;
    r[0] = f2s(f0.x); r[1] = f2s(f0.y); r[2] = f2s(f0.z); r[3] = f2s(f0.w);
    r[4] = f2s(f1.x); r[5] = f2s(f1.y); r[6] = f2s(f1.z); r[7] = f2s(f1.w);
    return r;
}
// async global->LDS DMA, 16B per lane (dest must be linear: base + lane*16)
__device__ __forceinline__ void ld16_lds(void* lds, const void* gsrc) {
    __builtin_amdgcn_global_load_lds(
        (const __attribute__((address_space(1))) unsigned int*)gsrc,
        (__attribute__((address_space(3))) unsigned int*)lds,
        16, 0, 0);
}

// ---------------- K1: hA GEMM (f32-direct, REP-amplified) || fill || p0p1+atomcvt || gru-weight cvt ----
__global__ __launch_bounds__(256) void k1_kernel(
    const float* __restrict__ atom,
    const float* __restrict__ W_att, const float* __restrict__ bias,
    const float* __restrict__ g_t, const float* __restrict__ bb_t,
    const float* __restrict__ mn_t, const float* __restrict__ vr_t,
    short* __restrict__ hA,
    const int* __restrict__ src, const int* __restrict__ dst,
    int* __restrict__ cnt, int* __restrict__ dlist,
    const float* __restrict__ W_align, const float* __restrict__ b_align,
    const float* __restrict__ g_a, const float* __restrict__ bb_a,
    const float* __restrict__ mn_a, const float* __restrict__ vr_a,
    float* __restrict__ p0p, float* __restrict__ p1p,
    short* __restrict__ atom_bf,
    const float* __restrict__ Wi, short* __restrict__ Wi_bf,
    const float* __restrict__ Wh, short* __restrict__ Wh_bf,
    int N, int E, int NB, int HB, int FB, int PB)
{
    int tid = threadIdx.x;
    int b = blockIdx.x;
    if (b < HB) {
        // ---- hA = BN(atom @ W_att^T + b_att) ----
        __shared__ short Bs[2048 * 8];       // 32KB, lane-ordered chunks
        int cb = b & 3, gg = b >> 2;
        if (gg >= NB) return;
        int c0 = cb * 64;
        int wave = tid >> 6, lane = tid & 63;
        int quad = lane >> 4, l15 = lane & 15;
        int m0 = gg * 128 + wave * 16;
        int ar0 = m0 + l15;       if (ar0 > N - 1) ar0 = N - 1;
        int ar1 = m0 + 64 + l15;  if (ar1 > N - 1) ar1 = N - 1;
        const float* ap0 = atom + (size_t)ar0 * D + quad * 8;
        const float* ap1 = atom + (size_t)ar1 * D + quad * 8;
        const short* lb = &Bs[lane * 8];

        for (int rep = 0; rep < REP; ++rep) {
            for (int c = tid; c < 2048; c += 256) {
                int l15c = c & 15, quadc = (c >> 4) & 3, t2 = c >> 6;
                int kkc = t2 & 7, jc = t2 >> 3;
                *(bf16x8*)(&Bs[c * 8]) =
                    cvt8(W_att + (size_t)(c0 + jc * 16 + l15c) * D + quadc * 8 + kkc * 32);
            }
            __syncthreads();

            f32x4 acc[2][4];
            #pragma unroll
            for (int t = 0; t < 2; t++)
                #pragma unroll
                for (int j = 0; j < 4; j++) acc[t][j] = (f32x4){0,0,0,0};
            #pragma unroll
            for (int kk = 0; kk < 8; kk++) {
                bf16x8 a0 = cvt8(ap0 + kk * 32);
                bf16x8 a1 = cvt8(ap1 + kk * 32);
                bf16x8 b0 = *(const bf16x8*)(lb + (0 * 8 + kk) * 512);
                bf16x8 b1 = *(const bf16x8*)(lb + (1 * 8 + kk) * 512);
                bf16x8 b2 = *(const bf16x8*)(lb + (2 * 8 + kk) * 512);
                bf16x8 b3 = *(const bf16x8*)(lb + (3 * 8 + kk) * 512);
                acc[0][0] = MFMA(a0, b0, acc[0][0], 0, 0, 0);
                acc[0][1] = MFMA(a0, b1, acc[0][1], 0, 0, 0);
                acc[0][2] = MFMA(a0, b2, acc[0][2], 0, 0, 0);
                acc[0][3] = MFMA(a0, b3, acc[0][3], 0, 0, 0);
                acc[1][0] = MFMA(a1, b0, acc[1][0], 0, 0, 0);
                acc[1][1] = MFMA(a1, b1, acc[1][1], 0, 0, 0);
                acc[1][2] = MFMA(a1, b2, acc[1][2], 0, 0, 0);
                acc[1][3] = MFMA(a1, b3, acc[1][3], 0, 0, 0);
            }
            #pragma unroll
            for (int j = 0; j < 4; j++) {
                int col = c0 + j * 16 + l15;
                float sc = rsqrtf(vr_t[col] + 1e-6f) * g_t[col];
                float sh = bb_t[col] - mn_t[col] * sc;
                float bi_ = bias[col];
                #pragma unroll
                for (int t = 0; t < 2; t++) {
                    #pragma unroll
                    for (int r = 0; r < 4; r++) {
                        int row = m0 + t * 64 + quad * 4 + r;
                        if (row < N) hA[(size_t)row * D + col] = f2s((acc[t][j][r] + bi_) * sc + sh);
                    }
                }
            }
            __syncthreads();
            asm volatile("" ::: "memory");
        }
        return;
    }
    b -= HB;
    if (b < FB) {
        // ---- bucket fill (NOT amplified: atomics) ----
        int e = b * 256 + tid;
        if (e < E) {
            int s = src[e];
            int p = atomicAdd(&cnt[s], 1);
            if (p < CAP) dlist[(s << 6) + p] = dst[e];
        }
        return;
    }
    b -= FB;
    if (b < PB) {
        // ---- p0p1 + atom->bf16 cvt ----
        int wave = tid >> 6, lane = tid & 63;
        int row = b * 4 + wave;
        if (row >= N) return;
        float4 a = *(const float4*)(atom + (size_t)row * D + lane * 4);
        s16x4 o; o[0] = f2s(a.x); o[1] = f2s(a.y); o[2] = f2s(a.z); o[3] = f2s(a.w);
        ((s16x4*)(atom_bf + (size_t)row * D))[lane] = o;
        float4 w0 = *(const float4*)(W_align + lane * 4);
        float4 w1 = *(const float4*)(W_align + D + lane * 4);
        float d0 = a.x * w0.x + a.y * w0.y + a.z * w0.z + a.w * w0.w;
        float d1 = a.x * w1.x + a.y * w1.y + a.z * w1.z + a.w * w1.w;
        #pragma unroll
        for (int s = 32; s > 0; s >>= 1) {
            d0 += __shfl_xor(d0, s, 64);
            d1 += __shfl_xor(d1, s, 64);
        }
        if (lane == 0) {
            float A = rsqrtf(vr_a[0] + 1e-6f) * g_a[0];
            p0p[row] = A * (d0 + b_align[0]) + bb_a[0] - A * mn_a[0];
            p1p[row] = A * d1;
        }
        return;
    }
    b -= PB;
    {
        // ---- W_ih / W_hh -> bf16 cvt ----
        int nG4 = 3 * D * D / 4;
        int j = b * 256 + tid;
        const float* srcp; short* dstp;
        if (j < nG4) { srcp = Wi; dstp = Wi_bf; }
        else { j -= nG4; if (j >= nG4) return; srcp = Wh; dstp = Wh_bf; }
        float4 v = ((const float4*)srcp)[j];
        s16x4 o; o[0] = f2s(v.x); o[1] = f2s(v.y); o[2] = f2s(v.z); o[3] = f2s(v.w);
        ((s16x4*)dstp)[j] = o;
    }
}

// ---------------- K2: fused score+softmax+aggregate (REP-amplified) ----------------
__global__ __launch_bounds__(256) void agg_kernel(
    const int* __restrict__ cnt, const int* __restrict__ dlist,
    const float* __restrict__ p0p, const float* __restrict__ p1p,
    const short* __restrict__ hA, short* __restrict__ ctx, int N)
{
    int w = (blockIdx.x * blockDim.x + threadIdx.x) >> 6;
    int lane = threadIdx.x & 63;
    if (w >= N) return;
    for (int rep = 0; rep < REP; ++rep) {
        int deg = cnt[w]; if (deg > CAP) deg = CAP;
        int base = w << 6;
        int d = 0; float e = 0.f;
        if (lane < deg) {
            d = dlist[base + lane];
            float x = p0p[w] + p1p[d];
            x = x > 0.f ? x : 0.01f * x;
            e = __expf(x);
        }
        float se = e;
        #pragma unroll
        for (int s = 32; s > 0; s >>= 1) se += __shfl_xor(se, s, 64);

        int grp = lane >> 4, l16 = lane & 15;
        float acc[16];
        #pragma unroll
        for (int i = 0; i < 16; i++) acc[i] = 0.f;
        int nit = (deg + 3) >> 2;
        for (int it = 0; it < nit; ++it) {
            int j = it * 4 + grp;
            int jc = j < deg ? j : 0;
            int dj = __shfl(d, jc, 64);
            float ej = __shfl(e, jc, 64);
            if (j >= deg) ej = 0.f;
            const short* hp = hA + (size_t)dj * D + l16 * 16;
            bf16x8 h0 = *(const bf16x8*)(hp);
            bf16x8 h1 = *(const bf16x8*)(hp + 8);
            #pragma unroll
            for (int i = 0; i < 8; i++) acc[i]     += ej * s2f(h0[i]);
            #pragma unroll
            for (int i = 0; i < 8; i++) acc[8 + i] += ej * s2f(h1[i]);
        }
        #pragma unroll
        for (int i = 0; i < 16; i++) {
            acc[i] += __shfl_xor(acc[i], 16, 64);
            acc[i] += __shfl_xor(acc[i], 32, 64);
        }
        if (grp == 0) {
            float inv = 1.f / (se + 1e-8f);
            bf16x8 o0, o1;
            #pragma unroll
            for (int i = 0; i < 8; i++) {
                float v0 = acc[i] * inv;
                v0 = v0 > 0.f ? v0 : __expf(v0) - 1.f;
                o0[i] = f2s(v0);
                float v1 = acc[8 + i] * inv;
                v1 = v1 > 0.f ? v1 : __expf(v1) - 1.f;
                o1[i] = f2s(v1);
            }
            short* cp = ctx + (size_t)w * D + l16 * 16;
            *(bf16x8*)cp = o0;
            *(bf16x8*)(cp + 8) = o1;
        }
        asm volatile("" ::: "memory");
    }
}

// ---------------- K3: fused GRU cell (REP-amplified) ----------------
__global__ __launch_bounds__(256) void gru_kernel(
    const short* __restrict__ ctx, const short* __restrict__ atom_bf,
    const short* __restrict__ W_ih, const short* __restrict__ W_hh,
    const float* __restrict__ b_ih, const float* __restrict__ b_hh,
    float* __restrict__ out, int N, int NB)
{
    __shared__ short Bs[3072 * 8];   // 48KB, lane-ordered chunks
    int bi = blockIdx.x;
    int xcd = bi & 7, rest = bi >> 3;
    int cb = rest & 15, gh = rest >> 4;
    int gg = gh * 8 + xcd;
    if (gg >= NB) return;
    int c0 = cb * 16;
    int tid = threadIdx.x;

    int wave = tid >> 6, lane = tid & 63;
    int quad = lane >> 4, l15 = lane & 15;
    int m0 = gg * 128 + wave * 16;
    int ar0 = m0 + l15;       if (ar0 > N - 1) ar0 = N - 1;
    int ar1 = m0 + 64 + l15;  if (ar1 > N - 1) ar1 = N - 1;
    const short* cp0 = ctx + (size_t)ar0 * D + quad * 8;
    const short* ap0 = atom_bf + (size_t)ar0 * D + quad * 8;
    const short* cp1 = ctx + (size_t)ar1 * D + quad * 8;
    const short* ap1 = atom_bf + (size_t)ar1 * D + quad * 8;
    int col = c0 + l15;
    const short* lb = &Bs[lane * 8];

    for (int rep = 0; rep < REP; ++rep) {
        // prefetch kk=0 A-operands BEFORE the stage
        bf16x8 c0v = *(const bf16x8*)(cp0);
        bf16x8 a0v = *(const bf16x8*)(ap0);
        bf16x8 c1v = *(const bf16x8*)(cp1);
        bf16x8 a1v = *(const bf16x8*)(ap1);

        // async stage: dest linear (base + lane*16), per-lane global source
        #pragma unroll
        for (int it = 0; it < 12; it++) {
            int c = tid + it * 256;
            int l15c = c & 15, quadc = (c >> 4) & 3, t2 = c >> 6;
            int kkc = t2 & 7, gate = t2 >> 3;
            const short* srcp = (gate < 3)
                ? W_ih + (size_t)(gate * 256 + c0 + l15c) * D + quadc * 8 + kkc * 32
                : W_hh + (size_t)((gate - 3) * 256 + c0 + l15c) * D + quadc * 8 + kkc * 32;
            ld16_lds(&Bs[c * 8], srcp);
        }
        __syncthreads();

        f32x4 gi[2][3], gh_[2][3];
        #pragma unroll
        for (int t = 0; t < 2; t++)
            #pragma unroll
            for (int j = 0; j < 3; j++) { gi[t][j] = (f32x4){0,0,0,0}; gh_[t][j] = (f32x4){0,0,0,0}; }
        #pragma unroll
        for (int kk = 0; kk < 8; kk++) {
            bf16x8 nc0, na0, nc1, na1;
            if (kk < 7) {
                int k = (kk + 1) * 32;
                nc0 = *(const bf16x8*)(cp0 + k);
                na0 = *(const bf16x8*)(ap0 + k);
                nc1 = *(const bf16x8*)(cp1 + k);
                na1 = *(const bf16x8*)(ap1 + k);
            }
            bf16x8 bir = *(const bf16x8*)(lb + (0 * 8 + kk) * 512);
            bf16x8 biz = *(const bf16x8*)(lb + (1 * 8 + kk) * 512);
            bf16x8 bin = *(const bf16x8*)(lb + (2 * 8 + kk) * 512);
            bf16x8 bhr = *(const bf16x8*)(lb + (3 * 8 + kk) * 512);
            bf16x8 bhz = *(const bf16x8*)(lb + (4 * 8 + kk) * 512);
            bf16x8 bhn = *(const bf16x8*)(lb + (5 * 8 + kk) * 512);
            gi[0][0] = MFMA(c0v, bir, gi[0][0], 0, 0, 0);
            gi[0][1] = MFMA(c0v, biz, gi[0][1], 0, 0, 0);
            gi[0][2] = MFMA(c0v, bin, gi[0][2], 0, 0, 0);
            gh_[0][0] = MFMA(a0v, bhr, gh_[0][0], 0, 0, 0);
            gh_[0][1] = MFMA(a0v, bhz, gh_[0][1], 0, 0, 0);
            gh_[0][2] = MFMA(a0v, bhn, gh_[0][2], 0, 0, 0);
            gi[1][0] = MFMA(c1v, bir, gi[1][0], 0, 0, 0);
            gi[1][1] = MFMA(c1v, biz, gi[1][1], 0, 0, 0);
            gi[1][2] = MFMA(c1v, bin, gi[1][2], 0, 0, 0);
            gh_[1][0] = MFMA(a1v, bhr, gh_[1][0], 0, 0, 0);
            gh_[1][1] = MFMA(a1v, bhz, gh_[1][1], 0, 0, 0);
            gh_[1][2] = MFMA(a1v, bhn, gh_[1][2], 0, 0, 0);
            if (kk < 7) { c0v = nc0; a0v = na0; c1v = nc1; a1v = na1; }
        }
        float bir_s = b_ih[col], biz_s = b_ih[col + 256], bin_s = b_ih[col + 512];
        float bhr_s = b_hh[col], bhz_s = b_hh[col + 256], bhn_s = b_hh[col + 512];
        #pragma unroll
        for (int t = 0; t < 2; t++) {
            #pragma unroll
            for (int r = 0; r < 4; r++) {
                int row = m0 + t * 64 + quad * 4 + r;
                if (row < N) {
                    float rr = 1.f / (1.f + __expf(-(gi[t][0][r] + bir_s + gh_[t][0][r] + bhr_s)));
                    float zz = 1.f / (1.f + __expf(-(gi[t][1][r] + biz_s + gh_[t][1][r] + bhz_s)));
                    float nn = tanhf(gi[t][2][r] + bin_s + rr * (gh_[t][2][r] + bhn_s));
                    float at = s2f(atom_bf[(size_t)row * D + col]);
                    out[(size_t)row * D + col] = (1.f - zz) * nn + zz * at;
                }
            }
        }
        __syncthreads();
        asm volatile("" ::: "memory");
    }
}

extern "C" void kernel_launch(void* const* d_in, const int* in_sizes, int n_in,
                              void* d_out, int out_size, void* d_ws, size_t ws_size,
                              hipStream_t stream) {
    const float* atom    = (const float*)d_in[0];
    const int*   bond    = (const int*)d_in[1];
    const float* W_align = (const float*)d_in[2];
    const float* b_align = (const float*)d_in[3];
    const float* bn_a_g  = (const float*)d_in[4];
    const float* bn_a_b  = (const float*)d_in[5];
    const float* bn_a_m  = (const float*)d_in[6];
    const float* bn_a_v  = (const float*)d_in[7];
    const float* W_att   = (const float*)d_in[8];
    const float* b_att   = (const float*)d_in[9];
    const float* bn_t_g  = (const float*)d_in[10];
    const float* bn_t_b  = (const float*)d_in[11];
    const float* bn_t_m  = (const float*)d_in[12];
    const float* bn_t_v  = (const float*)d_in[13];
    const float* W_ih    = (const float*)d_in[14];
    const float* W_hh    = (const float*)d_in[15];
    const float* b_ih    = (const float*)d_in[16];
    const float* b_hh    = (const float*)d_in[17];

    int N = in_sizes[0] / D;
    int E = in_sizes[1] / 2;
    const int* src = bond;
    const int* dst = bond + E;

    char* w = (char*)d_ws;
    size_t o = 0;
    auto alloc = [&](size_t bytes) {
        void* p = w + o;
        o = (o + bytes + 255) & ~(size_t)255;
        return p;
    };
    int*   cnt     = (int*)alloc((size_t)N * 4);
    int*   dlist   = (int*)alloc((size_t)N * CAP * 4);
    float* p0p     = (float*)alloc((size_t)N * 4);
    float* p1p     = (float*)alloc((size_t)N * 4);
    short* hA      = (short*)alloc((size_t)N * D * 2);
    short* ctx     = (short*)alloc((size_t)N * D * 2);
    short* atom_bf = (short*)alloc((size_t)N * D * 2);
    short* Wih_bf  = (short*)alloc((size_t)3 * D * D * 2);
    short* Whh_bf  = (short*)alloc((size_t)3 * D * D * 2);

    int NB = (N + 127) / 128;       // 79
    int GH = (NB + 7) / 8;          // 10
    int HB = 4 * NB;                // 316  hA GEMM blocks
    int FB = (E + 255) / 256;       // 625  fill blocks
    int PB = (N + 3) / 4;           // 2500 p0p1+atomcvt blocks
    int WB = (2 * 3 * D * D / 4 + 255) / 256;  // 384 gru-weight cvt blocks

    hipMemsetAsync(cnt, 0, (size_t)N * 4, stream);
    k1_kernel<<<HB + FB + PB + WB, 256, 0, stream>>>(
        atom, W_att, b_att, bn_t_g, bn_t_b, bn_t_m, bn_t_v, hA,
        src, dst, cnt, dlist,
        W_align, b_align, bn_a_g, bn_a_b, bn_a_m, bn_a_v, p0p, p1p,
        atom_bf, W_ih, Wih_bf, W_hh, Whh_bf,
        N, E, NB, HB, FB, PB);
    agg_kernel<<<((size_t)N * 64 + 255) / 256, 256, 0, stream>>>(
        cnt, dlist, p0p, p1p, hA, ctx, N);
    gru_kernel<<<8 * 16 * GH, 256, 0, stream>>>(
        ctx, atom_bf, Wih_bf, Whh_bf, b_ih, b_hh, (float*)d_out, N, NB);
}

// Round 10
// 164.437 us; speedup vs baseline: 1.6313x; 1.6313x over previous
//
#include <hip/hip_runtime.h>
#include <hip/hip_bf16.h>

#define D 256
#define CAP 64          // per-atom bucket capacity; P(degree>64)<1e-15 for E=160K,N=10K

typedef __attribute__((ext_vector_type(8))) short bf16x8;
typedef __attribute__((ext_vector_type(4))) short s16x4;
typedef __attribute__((ext_vector_type(4))) float f32x4;

#define MFMA __builtin_amdgcn_mfma_f32_16x16x32_bf16

__device__ __forceinline__ float s2f(short u) {
    union { unsigned int i; float f; } c;
    c.i = ((unsigned int)(unsigned short)u) << 16;
    return c.f;
}
__device__ __forceinline__ short f2s(float f) {
    union { float f; unsigned int u; } c; c.f = f;
    unsigned int u = c.u;
    u += 0x7fffu + ((u >> 16) & 1u);
    return (short)(u >> 16);
}
// convert 8 contiguous f32 -> bf16x8
__device__ __forceinline__ bf16x8 cvt8(const float* p) {
    float4 f0 = *(const float4*)p;
    float4 f1 = *(const float4*)(p + 4);
    bf16x8 r;
    r[0] = f2s(f0.x); r[1] = f2s(f0.y); r[2] = f2s(f0.z); r[3] = f2s(f0.w);
    r[4] = f2s(f1.x); r[5] = f2s(f1.y); r[6] = f2s(f1.z); r[7] = f2s(f1.w);
    return r;
}
// async global->LDS DMA, 16B per lane (dest must be linear: base + lane*16)
__device__ __forceinline__ void ld16_lds(void* lds, const void* gsrc) {
    __builtin_amdgcn_global_load_lds(
        (const __attribute__((address_space(1))) unsigned int*)gsrc,
        (__attribute__((address_space(3))) unsigned int*)lds,
        16, 0, 0);
}
// single-instruction approx reciprocal (~1 ulp; absmax tol 1.5e-2)
__device__ __forceinline__ float frcp(float x) {
    float r;
    asm volatile("v_rcp_f32 %0, %1" : "=v"(r) : "v"(x));
    return r;
}
// fast sigmoid / tanh via v_exp + v_rcp (replaces libm tanhf: ~50 instr -> ~6)
__device__ __forceinline__ float fsigmoid(float x) {
    return frcp(1.f + __expf(-x));
}
__device__ __forceinline__ float ftanh(float x) {
    x = fminf(fmaxf(x, -10.f), 10.f);     // clamp: avoid inf/inf (tanh(10)=1-4e-9)
    float e = __expf(2.f * x);
    return (e - 1.f) * frcp(e + 1.f);
}

// ---------------- K1: hA GEMM (f32-direct) || fill || p0p1+atomcvt || gru-weight cvt ----
// Only precondition: cnt zeroed (hipMemsetAsync). All four works mutually independent.
__global__ __launch_bounds__(256) void k1_kernel(
    const float* __restrict__ atom,
    const float* __restrict__ W_att, const float* __restrict__ bias,
    const float* __restrict__ g_t, const float* __restrict__ bb_t,
    const float* __restrict__ mn_t, const float* __restrict__ vr_t,
    short* __restrict__ hA,
    const int* __restrict__ src, const int* __restrict__ dst,
    int* __restrict__ cnt, int* __restrict__ dlist,
    const float* __restrict__ W_align, const float* __restrict__ b_align,
    const float* __restrict__ g_a, const float* __restrict__ bb_a,
    const float* __restrict__ mn_a, const float* __restrict__ vr_a,
    float* __restrict__ p0p, float* __restrict__ p1p,
    short* __restrict__ atom_bf,
    const float* __restrict__ Wi, short* __restrict__ Wi_bf,
    const float* __restrict__ Wh, short* __restrict__ Wh_bf,
    int N, int E, int NB, int HB, int FB, int PB)
{
    int tid = threadIdx.x;
    int b = blockIdx.x;
    if (b < HB) {
        // ---- hA = BN(atom @ W_att^T + b_att), on-the-fly f32->bf16 ----
        __shared__ short Bs[2048 * 8];       // 32KB, lane-ordered chunks
        int cb = b & 3, gg = b >> 2;
        if (gg >= NB) return;
        int c0 = cb * 64;
        for (int c = tid; c < 2048; c += 256) {
            int l15c = c & 15, quadc = (c >> 4) & 3, t2 = c >> 6;
            int kkc = t2 & 7, jc = t2 >> 3;
            *(bf16x8*)(&Bs[c * 8]) =
                cvt8(W_att + (size_t)(c0 + jc * 16 + l15c) * D + quadc * 8 + kkc * 32);
        }
        __syncthreads();

        int wave = tid >> 6, lane = tid & 63;
        int quad = lane >> 4, l15 = lane & 15;
        int m0 = gg * 128 + wave * 16;
        int ar0 = m0 + l15;       if (ar0 > N - 1) ar0 = N - 1;
        int ar1 = m0 + 64 + l15;  if (ar1 > N - 1) ar1 = N - 1;
        const float* ap0 = atom + (size_t)ar0 * D + quad * 8;
        const float* ap1 = atom + (size_t)ar1 * D + quad * 8;
        const short* lb = &Bs[lane * 8];
        f32x4 acc[2][4];
        #pragma unroll
        for (int t = 0; t < 2; t++)
            #pragma unroll
            for (int j = 0; j < 4; j++) acc[t][j] = (f32x4){0,0,0,0};
        #pragma unroll
        for (int kk = 0; kk < 8; kk++) {
            bf16x8 a0 = cvt8(ap0 + kk * 32);
            bf16x8 a1 = cvt8(ap1 + kk * 32);
            bf16x8 b0 = *(const bf16x8*)(lb + (0 * 8 + kk) * 512);
            bf16x8 b1 = *(const bf16x8*)(lb + (1 * 8 + kk) * 512);
            bf16x8 b2 = *(const bf16x8*)(lb + (2 * 8 + kk) * 512);
            bf16x8 b3 = *(const bf16x8*)(lb + (3 * 8 + kk) * 512);
            acc[0][0] = MFMA(a0, b0, acc[0][0], 0, 0, 0);
            acc[0][1] = MFMA(a0, b1, acc[0][1], 0, 0, 0);
            acc[0][2] = MFMA(a0, b2, acc[0][2], 0, 0, 0);
            acc[0][3] = MFMA(a0, b3, acc[0][3], 0, 0, 0);
            acc[1][0] = MFMA(a1, b0, acc[1][0], 0, 0, 0);
            acc[1][1] = MFMA(a1, b1, acc[1][1], 0, 0, 0);
            acc[1][2] = MFMA(a1, b2, acc[1][2], 0, 0, 0);
            acc[1][3] = MFMA(a1, b3, acc[1][3], 0, 0, 0);
        }
        #pragma unroll
        for (int j = 0; j < 4; j++) {
            int col = c0 + j * 16 + l15;
            float sc = rsqrtf(vr_t[col] + 1e-6f) * g_t[col];
            float sh = bb_t[col] - mn_t[col] * sc;
            float bi_ = bias[col];
            #pragma unroll
            for (int t = 0; t < 2; t++) {
                #pragma unroll
                for (int r = 0; r < 4; r++) {
                    int row = m0 + t * 64 + quad * 4 + r;
                    if (row < N) hA[(size_t)row * D + col] = f2s((acc[t][j][r] + bi_) * sc + sh);
                }
            }
        }
        return;
    }
    b -= HB;
    if (b < FB) {
        // ---- bucket fill ----
        int e = b * 256 + tid;
        if (e < E) {
            int s = src[e];
            int p = atomicAdd(&cnt[s], 1);
            if (p < CAP) dlist[(s << 6) + p] = dst[e];
        }
        return;
    }
    b -= FB;
    if (b < PB) {
        // ---- p0p1 + atom->bf16 cvt: 16 lanes per row, 16 rows per block ----
        int wave = tid >> 6, lane = tid & 63;
        int sub = lane & 15;
        int row = b * 16 + wave * 4 + (lane >> 4);
        if (row >= N) return;
        const float* ap = atom + (size_t)row * D + sub * 16;
        float4 a0 = *(const float4*)(ap);
        float4 a1 = *(const float4*)(ap + 4);
        float4 a2 = *(const float4*)(ap + 8);
        float4 a3 = *(const float4*)(ap + 12);
        // atom -> bf16 (two 16B stores per lane)
        short* op = atom_bf + (size_t)row * D + sub * 16;
        bf16x8 o0, o1;
        o0[0]=f2s(a0.x); o0[1]=f2s(a0.y); o0[2]=f2s(a0.z); o0[3]=f2s(a0.w);
        o0[4]=f2s(a1.x); o0[5]=f2s(a1.y); o0[6]=f2s(a1.z); o0[7]=f2s(a1.w);
        o1[0]=f2s(a2.x); o1[1]=f2s(a2.y); o1[2]=f2s(a2.z); o1[3]=f2s(a2.w);
        o1[4]=f2s(a3.x); o1[5]=f2s(a3.y); o1[6]=f2s(a3.z); o1[7]=f2s(a3.w);
        *(bf16x8*)op = o0;
        *(bf16x8*)(op + 8) = o1;
        // align-score partial dots
        const float* w0p = W_align + sub * 16;
        const float* w1p = W_align + D + sub * 16;
        float4 w00 = *(const float4*)(w0p),     w01 = *(const float4*)(w0p + 4);
        float4 w02 = *(const float4*)(w0p + 8), w03 = *(const float4*)(w0p + 12);
        float4 w10 = *(const float4*)(w1p),     w11 = *(const float4*)(w1p + 4);
        float4 w12 = *(const float4*)(w1p + 8), w13 = *(const float4*)(w1p + 12);
        float d0 = a0.x*w00.x + a0.y*w00.y + a0.z*w00.z + a0.w*w00.w
                 + a1.x*w01.x + a1.y*w01.y + a1.z*w01.z + a1.w*w01.w
                 + a2.x*w02.x + a2.y*w02.y + a2.z*w02.z + a2.w*w02.w
                 + a3.x*w03.x + a3.y*w03.y + a3.z*w03.z + a3.w*w03.w;
        float d1 = a0.x*w10.x + a0.y*w10.y + a0.z*w10.z + a0.w*w10.w
                 + a1.x*w11.x + a1.y*w11.y + a1.z*w11.z + a1.w*w11.w
                 + a2.x*w12.x + a2.y*w12.y + a2.z*w12.z + a2.w*w12.w
                 + a3.x*w13.x + a3.y*w13.y + a3.z*w13.z + a3.w*w13.w;
        #pragma unroll
        for (int s = 1; s < 16; s <<= 1) {
            d0 += __shfl_xor(d0, s, 64);
            d1 += __shfl_xor(d1, s, 64);
        }
        if (sub == 0) {
            float A = rsqrtf(vr_a[0] + 1e-6f) * g_a[0];
            p0p[row] = A * (d0 + b_align[0]) + bb_a[0] - A * mn_a[0];
            p1p[row] = A * d1;
        }
        return;
    }
    b -= PB;
    {
        // ---- W_ih / W_hh -> bf16 cvt ----
        int nG4 = 3 * D * D / 4;
        int j = b * 256 + tid;
        const float* srcp; short* dstp;
        if (j < nG4) { srcp = Wi; dstp = Wi_bf; }
        else { j -= nG4; if (j >= nG4) return; srcp = Wh; dstp = Wh_bf; }
        float4 v = ((const float4*)srcp)[j];
        s16x4 o; o[0] = f2s(v.x); o[1] = f2s(v.y); o[2] = f2s(v.z); o[3] = f2s(v.w);
        ((s16x4*)dstp)[j] = o;
    }
}

// ---------------- K2: fused score+softmax+aggregate ----------------
__global__ __launch_bounds__(256) void agg_kernel(
    const int* __restrict__ cnt, const int* __restrict__ dlist,
    const float* __restrict__ p0p, const float* __restrict__ p1p,
    const short* __restrict__ hA, short* __restrict__ ctx, int N)
{
    int w = (blockIdx.x * blockDim.x + threadIdx.x) >> 6;
    int lane = threadIdx.x & 63;
    if (w >= N) return;
    int deg = cnt[w]; if (deg > CAP) deg = CAP;
    int base = w << 6;
    int d = 0; float e = 0.f;
    if (lane < deg) {
        d = dlist[base + lane];
        float x = p0p[w] + p1p[d];
        x = x > 0.f ? x : 0.01f * x;
        e = __expf(x);
    }
    float se = e;
    #pragma unroll
    for (int s = 32; s > 0; s >>= 1) se += __shfl_xor(se, s, 64);

    int grp = lane >> 4, l16 = lane & 15;
    float acc[16];
    #pragma unroll
    for (int i = 0; i < 16; i++) acc[i] = 0.f;
    int nit = (deg + 3) >> 2;
    for (int it = 0; it < nit; ++it) {
        int j = it * 4 + grp;
        int jc = j < deg ? j : 0;
        int dj = __shfl(d, jc, 64);
        float ej = __shfl(e, jc, 64);
        if (j >= deg) ej = 0.f;
        const short* hp = hA + (size_t)dj * D + l16 * 16;
        bf16x8 h0 = *(const bf16x8*)(hp);
        bf16x8 h1 = *(const bf16x8*)(hp + 8);
        #pragma unroll
        for (int i = 0; i < 8; i++) acc[i]     += ej * s2f(h0[i]);
        #pragma unroll
        for (int i = 0; i < 8; i++) acc[8 + i] += ej * s2f(h1[i]);
    }
    #pragma unroll
    for (int i = 0; i < 16; i++) {
        acc[i] += __shfl_xor(acc[i], 16, 64);
        acc[i] += __shfl_xor(acc[i], 32, 64);
    }
    if (grp == 0) {
        float inv = frcp(se + 1e-8f);
        bf16x8 o0, o1;
        #pragma unroll
        for (int i = 0; i < 8; i++) {
            float v0 = acc[i] * inv;
            v0 = v0 > 0.f ? v0 : __expf(v0) - 1.f;
            o0[i] = f2s(v0);
            float v1 = acc[8 + i] * inv;
            v1 = v1 > 0.f ? v1 : __expf(v1) - 1.f;
            o1[i] = f2s(v1);
        }
        short* cp = ctx + (size_t)w * D + l16 * 16;
        *(bf16x8*)cp = o0;
        *(bf16x8*)(cp + 8) = o1;
    }
}

// ---------------- K3: fused GRU cell, async LDS stage + A-prefetch + fast epilogue ----
__global__ __launch_bounds__(256) void gru_kernel(
    const short* __restrict__ ctx, const short* __restrict__ atom_bf,
    const short* __restrict__ W_ih, const short* __restrict__ W_hh,
    const float* __restrict__ b_ih, const float* __restrict__ b_hh,
    float* __restrict__ out, int N, int NB)
{
    __shared__ short Bs[3072 * 8];   // 48KB, lane-ordered chunks
    int bi = blockIdx.x;
    int xcd = bi & 7, rest = bi >> 3;
    int cb = rest & 15, gh = rest >> 4;
    int gg = gh * 8 + xcd;
    if (gg >= NB) return;
    int c0 = cb * 16;
    int tid = threadIdx.x;

    int wave = tid >> 6, lane = tid & 63;
    int quad = lane >> 4, l15 = lane & 15;
    int m0 = gg * 128 + wave * 16;
    int ar0 = m0 + l15;       if (ar0 > N - 1) ar0 = N - 1;
    int ar1 = m0 + 64 + l15;  if (ar1 > N - 1) ar1 = N - 1;
    const short* cp0 = ctx + (size_t)ar0 * D + quad * 8;
    const short* ap0 = atom_bf + (size_t)ar0 * D + quad * 8;
    const short* cp1 = ctx + (size_t)ar1 * D + quad * 8;
    const short* ap1 = atom_bf + (size_t)ar1 * D + quad * 8;

    // prefetch kk=0 A-operands BEFORE the stage: latency hides under stage issue
    bf16x8 c0v = *(const bf16x8*)(cp0);
    bf16x8 a0v = *(const bf16x8*)(ap0);
    bf16x8 c1v = *(const bf16x8*)(cp1);
    bf16x8 a1v = *(const bf16x8*)(ap1);

    // async stage: dest linear (base + lane*16), per-lane global source
    #pragma unroll
    for (int it = 0; it < 12; it++) {
        int c = tid + it * 256;
        int l15c = c & 15, quadc = (c >> 4) & 3, t2 = c >> 6;
        int kkc = t2 & 7, gate = t2 >> 3;
        const short* srcp = (gate < 3)
            ? W_ih + (size_t)(gate * 256 + c0 + l15c) * D + quadc * 8 + kkc * 32
            : W_hh + (size_t)((gate - 3) * 256 + c0 + l15c) * D + quadc * 8 + kkc * 32;
        ld16_lds(&Bs[c * 8], srcp);
    }
    __syncthreads();

    const short* lb = &Bs[lane * 8];
    f32x4 gi[2][3], gh_[2][3];
    #pragma unroll
    for (int t = 0; t < 2; t++)
        #pragma unroll
        for (int j = 0; j < 3; j++) { gi[t][j] = (f32x4){0,0,0,0}; gh_[t][j] = (f32x4){0,0,0,0}; }
    #pragma unroll
    for (int kk = 0; kk < 8; kk++) {
        bf16x8 nc0, na0, nc1, na1;
        if (kk < 7) {            // software-pipeline next A-fragments
            int k = (kk + 1) * 32;
            nc0 = *(const bf16x8*)(cp0 + k);
            na0 = *(const bf16x8*)(ap0 + k);
            nc1 = *(const bf16x8*)(cp1 + k);
            na1 = *(const bf16x8*)(ap1 + k);
        }
        bf16x8 bir = *(const bf16x8*)(lb + (0 * 8 + kk) * 512);
        bf16x8 biz = *(const bf16x8*)(lb + (1 * 8 + kk) * 512);
        bf16x8 bin = *(const bf16x8*)(lb + (2 * 8 + kk) * 512);
        bf16x8 bhr = *(const bf16x8*)(lb + (3 * 8 + kk) * 512);
        bf16x8 bhz = *(const bf16x8*)(lb + (4 * 8 + kk) * 512);
        bf16x8 bhn = *(const bf16x8*)(lb + (5 * 8 + kk) * 512);
        gi[0][0] = MFMA(c0v, bir, gi[0][0], 0, 0, 0);
        gi[0][1] = MFMA(c0v, biz, gi[0][1], 0, 0, 0);
        gi[0][2] = MFMA(c0v, bin, gi[0][2], 0, 0, 0);
        gh_[0][0] = MFMA(a0v, bhr, gh_[0][0], 0, 0, 0);
        gh_[0][1] = MFMA(a0v, bhz, gh_[0][1], 0, 0, 0);
        gh_[0][2] = MFMA(a0v, bhn, gh_[0][2], 0, 0, 0);
        gi[1][0] = MFMA(c1v, bir, gi[1][0], 0, 0, 0);
        gi[1][1] = MFMA(c1v, biz, gi[1][1], 0, 0, 0);
        gi[1][2] = MFMA(c1v, bin, gi[1][2], 0, 0, 0);
        gh_[1][0] = MFMA(a1v, bhr, gh_[1][0], 0, 0, 0);
        gh_[1][1] = MFMA(a1v, bhz, gh_[1][1], 0, 0, 0);
        gh_[1][2] = MFMA(a1v, bhn, gh_[1][2], 0, 0, 0);
        if (kk < 7) { c0v = nc0; a0v = na0; c1v = nc1; a1v = na1; }
    }
    int col = c0 + l15;
    float bir_s = b_ih[col], biz_s = b_ih[col + 256], bin_s = b_ih[col + 512];
    float bhr_s = b_hh[col], bhz_s = b_hh[col + 256], bhn_s = b_hh[col + 512];
    #pragma unroll
    for (int t = 0; t < 2; t++) {
        #pragma unroll
        for (int r = 0; r < 4; r++) {
            int row = m0 + t * 64 + quad * 4 + r;
            if (row < N) {
                float rr = fsigmoid(gi[t][0][r] + bir_s + gh_[t][0][r] + bhr_s);
                float zz = fsigmoid(gi[t][1][r] + biz_s + gh_[t][1][r] + bhz_s);
                float nn = ftanh(gi[t][2][r] + bin_s + rr * (gh_[t][2][r] + bhn_s));
                float at = s2f(atom_bf[(size_t)row * D + col]);
                out[(size_t)row * D + col] = (1.f - zz) * nn + zz * at;
            }
        }
    }
}

extern "C" void kernel_launch(void* const* d_in, const int* in_sizes, int n_in,
                              void* d_out, int out_size, void* d_ws, size_t ws_size,
                              hipStream_t stream) {
    const float* atom    = (const float*)d_in[0];
    const int*   bond    = (const int*)d_in[1];
    const float* W_align = (const float*)d_in[2];
    const float* b_align = (const float*)d_in[3];
    const float* bn_a_g  = (const float*)d_in[4];
    const float* bn_a_b  = (const float*)d_in[5];
    const float* bn_a_m  = (const float*)d_in[6];
    const float* bn_a_v  = (const float*)d_in[7];
    const float* W_att   = (const float*)d_in[8];
    const float* b_att   = (const float*)d_in[9];
    const float* bn_t_g  = (const float*)d_in[10];
    const float* bn_t_b  = (const float*)d_in[11];
    const float* bn_t_m  = (const float*)d_in[12];
    const float* bn_t_v  = (const float*)d_in[13];
    const float* W_ih    = (const float*)d_in[14];
    const float* W_hh    = (const float*)d_in[15];
    const float* b_ih    = (const float*)d_in[16];
    const float* b_hh    = (const float*)d_in[17];

    int N = in_sizes[0] / D;
    int E = in_sizes[1] / 2;
    const int* src = bond;
    const int* dst = bond + E;

    char* w = (char*)d_ws;
    size_t o = 0;
    auto alloc = [&](size_t bytes) {
        void* p = w + o;
        o = (o + bytes + 255) & ~(size_t)255;
        return p;
    };
    int*   cnt     = (int*)alloc((size_t)N * 4);
    int*   dlist   = (int*)alloc((size_t)N * CAP * 4);
    float* p0p     = (float*)alloc((size_t)N * 4);
    float* p1p     = (float*)alloc((size_t)N * 4);
    short* hA      = (short*)alloc((size_t)N * D * 2);
    short* ctx     = (short*)alloc((size_t)N * D * 2);
    short* atom_bf = (short*)alloc((size_t)N * D * 2);
    short* Wih_bf  = (short*)alloc((size_t)3 * D * D * 2);
    short* Whh_bf  = (short*)alloc((size_t)3 * D * D * 2);

    int NB = (N + 127) / 128;       // 79
    int GH = (NB + 7) / 8;          // 10
    int HB = 4 * NB;                // 316  hA GEMM blocks
    int FB = (E + 255) / 256;       // 625  fill blocks
    int PB = (N + 15) / 16;         // 625  p0p1+atomcvt blocks (16 rows/block)
    int WB = (2 * 3 * D * D / 4 + 255) / 256;  // 384 gru-weight cvt blocks

    hipMemsetAsync(cnt, 0, (size_t)N * 4, stream);
    k1_kernel<<<HB + FB + PB + WB, 256, 0, stream>>>(
        atom, W_att, b_att, bn_t_g, bn_t_b, bn_t_m, bn_t_v, hA,
        src, dst, cnt, dlist,
        W_align, b_align, bn_a_g, bn_a_b, bn_a_m, bn_a_v, p0p, p1p,
        atom_bf, W_ih, Wih_bf, W_hh, Whh_bf,
        N, E, NB, HB, FB, PB);
    agg_kernel<<<((size_t)N * 64 + 255) / 256, 256, 0, stream>>>(
        cnt, dlist, p0p, p1p, hA, ctx, N);
    gru_kernel<<<8 * 16 * GH, 256, 0, stream>>>(
        ctx, atom_bf, Wih_bf, Whh_bf, b_ih, b_hh, (float*)d_out, N, NB);
}